// Round 11
// baseline (166.017 us; speedup 1.0000x reference)
//
#include <hip/hip_runtime.h>
#include <hip/hip_bf16.h>
#include <float.h>
#include <math.h>

#define NPTS 500
#define NP12 12
#define NPP  4
#define SLOPE 0.01f

__device__ __forceinline__ float lrelu(float x) { return x > 0.f ? x : SLOPE * x; }

// ---------------------------------------------------------------------------
// prep_kernel: three independent task families in one dispatch (bid ranges):
//   [0,375)     knn: wave-per-query top-k + softmax numerators (r8-verified)
//   [375,503)   featchain: BOTH conv layers, self-contained per block
//               (r10-verified; x4 redundant 64x64 mid tile is trivial)
//   [503,1468)  compose: weight composition (r8-verified)
// ---------------------------------------------------------------------------
__global__ __launch_bounds__(256) void prep_kernel(
        const float* __restrict__ cloud, const float* __restrict__ cloud_tar,
        const float* __restrict__ img, const float* __restrict__ img_tar,
        const float* __restrict__ Wp1, const float* __restrict__ bp1,
        const float* __restrict__ Wp2, const float* __restrict__ bp2,
        const float* __restrict__ Wi1, const float* __restrict__ bi1,
        const float* __restrict__ Wi2, const float* __restrict__ bi2,
        const float* __restrict__ Wpn1, const float* __restrict__ bpn1,
        const float* __restrict__ Wpn2, const float* __restrict__ bpn2,
        const float* __restrict__ Wfc1, const float* __restrict__ bfc1,
        const float* __restrict__ Wfc2, const float* __restrict__ bfc2,
        const float* __restrict__ Wf2,  const float* __restrict__ bf2,
        int* __restrict__ inds, int* __restrict__ inds_self2, int* __restrict__ inds_pp,
        float* __restrict__ w_ct, float* __restrict__ w_cc, float* __restrict__ partials,
        float* __restrict__ P_ct, float* __restrict__ P_c,
        float* __restrict__ F_it, float* __restrict__ F_ic,
        float* __restrict__ Wcomb2, float* __restrict__ bcomb2,
        float* __restrict__ Wcomb1, float* __restrict__ bcomb1) {
    __shared__ __align__(16) float sm[6144];
    const int tid = threadIdx.x;
    const int bid = blockIdx.x;

    if (bid < 375) {
        // ---------------- knn task ----------------
        float* c_lds  = sm;
        float* ct_lds = sm + 1504;
        for (int i = tid; i < 1500; i += 256) {
            c_lds[i]  = cloud[i];
            ct_lds[i] = cloud_tar[i];
        }
        __syncthreads();

        const int wid  = bid * 4 + (tid >> 6);   // < 1500
        const int lane = tid & 63;
        const int prob = wid / NPTS;
        const int n    = wid % NPTS;

        const float* Q; const float* R; int k; int* out; float* w;
        if (prob == 0)      { Q = ct_lds; R = c_lds;  k = NP12; out = inds;       w = w_ct; }
        else if (prob == 1) { Q = ct_lds; R = ct_lds; k = NP12; out = inds_self2; w = w_cc; }
        else                { Q = c_lds;  R = ct_lds; k = NPP;  out = inds_pp;    w = nullptr; }

        const float qx = Q[n * 3 + 0];
        const float qy = Q[n * 3 + 1];
        const float qz = Q[n * 3 + 2];

        float d[8];
#pragma unroll
        for (int j = 0; j < 8; ++j) {
            int idx = j * 64 + lane;
            float dd = FLT_MAX;
            if (idx < NPTS) {
                float dx = qx - R[idx * 3 + 0];
                float dy = qy - R[idx * 3 + 1];
                float dz = qz - R[idx * 3 + 2];
                dd = dx * dx + dy * dy + dz * dz;
            }
            d[j] = dd;
        }

        float sum_e = 0.f;
        for (int t = 0; t < k; ++t) {
            float bv = d[0]; int bj = 0;
#pragma unroll
            for (int j = 1; j < 8; ++j) {
                if (d[j] < bv) { bv = d[j]; bj = j; }
            }
            int bidx = bj * 64 + lane;
#pragma unroll
            for (int s = 32; s >= 1; s >>= 1) {
                float ov = __shfl_xor(bv, s, 64);
                int   oi = __shfl_xor(bidx, s, 64);
                if (ov < bv || (ov == bv && oi < bidx)) { bv = ov; bidx = oi; }
            }
            if (w) {
                float e = expf(-sqrtf(bv + 1e-12f));
                sum_e += e;
                if (lane == 0) w[n * NP12 + t] = e;
            }
            if (lane == 0) out[n * k + t] = bidx;
            bool mine = (lane == (bidx & 63));
            int jj = bidx >> 6;
#pragma unroll
            for (int j = 0; j < 8; ++j) {
                if (mine && jj == j) d[j] = FLT_MAX;
            }
        }
        if (w && lane == 0) partials[wid] = sum_e;
        return;
    }

    if (bid < 503) {
        // ---------------- featchain task (both layers) ----------------
        const int f     = bid - 375;        // 0..127
        const int chain = f >> 5;           // 0..3
        const int sub   = f & 31;
        const int rowg  = sub >> 3;         // 0..3
        const int col0  = (sub & 7) * 64;
        float* xin = sm;                    // 32*64
        float* mid = sm + 2048;             // 64*64

        const int wave = __builtin_amdgcn_readfirstlane(tid >> 6);
        const int lane = tid & 63;

        const float *src, *W1, *B1, *W2, *B2;
        float* dst;
        int Cin; bool coord;
        switch (chain) {
            case 0: src = cloud_tar; W1 = Wp1; B1 = bp1; W2 = Wp2; B2 = bp2; dst = P_ct; Cin = 3;  coord = true;  break;
            case 1: src = cloud;     W1 = Wp1; B1 = bp1; W2 = Wp2; B2 = bp2; dst = P_c;  Cin = 3;  coord = true;  break;
            case 2: src = img_tar;   W1 = Wi1; B1 = bi1; W2 = Wi2; B2 = bi2; dst = F_it; Cin = 32; coord = false; break;
            default:src = img;       W1 = Wi1; B1 = bi1; W2 = Wi2; B2 = bi2; dst = F_ic; Cin = 32; coord = false; break;
        }

        for (int idx = tid; idx < Cin * 64; idx += 256) {
            int i = idx >> 6;
            int cl = idx & 63;
            int nn = col0 + cl;
            float v = 0.f;
            if (nn < NPTS) v = coord ? src[nn * 3 + i] : src[i * NPTS + nn];
            xin[i * 64 + cl] = v;
        }
        __syncthreads();

        {   // layer 1: full 64-row mid tile (wave -> 16 rows)
            const int m0 = wave * 16;
            float accm[16];
#pragma unroll
            for (int r = 0; r < 16; ++r) accm[r] = B1[m0 + r];
            for (int i = 0; i < Cin; ++i) {
                float xv = xin[i * 64 + lane];
#pragma unroll
                for (int r = 0; r < 16; ++r)
                    accm[r] = fmaf(W1[(m0 + r) * Cin + i], xv, accm[r]);
            }
#pragma unroll
            for (int r = 0; r < 16; ++r)
                mid[(m0 + r) * 64 + lane] = lrelu(accm[r]);
        }
        __syncthreads();

        {   // layer 2: this block's 32 rows (wave -> 8 rows)
            const int o0 = rowg * 32 + wave * 8;
            float acc[8];
#pragma unroll
            for (int r = 0; r < 8; ++r) acc[r] = B2[o0 + r];
#pragma unroll 16
            for (int m = 0; m < 64; ++m) {
                float xv = mid[m * 64 + lane];
#pragma unroll
                for (int r = 0; r < 8; ++r)
                    acc[r] = fmaf(W2[(o0 + r) * 64 + m], xv, acc[r]);
            }
            const int nn = col0 + lane;
            if (nn < NPTS) {
#pragma unroll
                for (int r = 0; r < 8; ++r)
                    dst[(o0 + r) * NPTS + nn] = acc[r];
            }
        }
        return;
    }

    // ---------------- compose task ----------------
    int e = (bid - 503) * 256 + tid;
    if (e < 163840) {                       // Wcomb2 = Wpn2 @ Wpn1
        int o = e / 160, j = e % 160;
        float acc = 0.f;
        for (int k = 0; k < 256; ++k)
            acc = fmaf(Wpn2[o * 256 + k], Wpn1[k * 160 + j], acc);
        Wcomb2[e] = acc;
        return;
    }
    e -= 163840;
    if (e < 81920) {                        // Wcomb1 = [Wf2L@Wfc2 | Wf2R@Wfc1]
        int o = e / 512, c = e % 512;
        float acc = 0.f;
        if (c < 256) {
            for (int m = 0; m < 64; ++m)
                acc = fmaf(Wf2[o * 128 + m], Wfc2[m * 256 + c], acc);
        } else {
            int cc = c - 256;
            for (int m = 0; m < 64; ++m)
                acc = fmaf(Wf2[o * 128 + 64 + m], Wfc1[m * 256 + cc], acc);
        }
        Wcomb1[o * 512 + c] = acc;
        return;
    }
    e -= 81920;
    if (e < 1024) {                         // bcomb2
        float acc = bpn2[e];
        for (int k = 0; k < 256; ++k)
            acc = fmaf(Wpn2[e * 256 + k], bpn1[k], acc);
        bcomb2[e] = acc;
        return;
    }
    e -= 1024;
    if (e < 160) {                          // bcomb1
        float acc = bf2[e];
        for (int m = 0; m < 64; ++m) {
            acc = fmaf(Wf2[e * 128 + m],      bfc2[m], acc);
            acc = fmaf(Wf2[e * 128 + 64 + m], bfc1[m], acc);
        }
        bcomb1[e] = acc;
    }
}

// ---------------------------------------------------------------------------
// diffsdiff: diff + sdiff fused. 256 blocks = (channel, column-half): block
// redundantly computes the FULL diff row into LDS (needed for the sdiff
// gather regardless) but writes global + gathers only its 250-col half —
// doubles CU coverage vs r10's 128 blocks and halves pass-2 per block.
// Writes dcat ([cd;sid;id;spd], 512x500) consumed by gemmA.
// ---------------------------------------------------------------------------
__global__ __launch_bounds__(256) void diffsdiff_kernel(
        const float* __restrict__ F_it, const float* __restrict__ F_ic,
        const float* __restrict__ P_ct, const float* __restrict__ P_c,
        const int* __restrict__ inds, const int* __restrict__ inds_self2,
        const float* __restrict__ w_ct, const float* __restrict__ w_cc,
        const float* __restrict__ partials,
        float* __restrict__ dcat) {
    __shared__ __align__(16) float sm[2056];
    float* sFic = sm;
    float* sPc  = sm + 512;
    float* sID  = sm + 1024;
    float* sCD  = sm + 1536;
    float* red  = sm + 2048;   // 8 floats
    const int tid = threadIdx.x;
    const int ch  = blockIdx.x >> 1;
    const int h   = blockIdx.x & 1;
    const int n0  = h * 250;

    float l0 = 0.f, l1 = 0.f;
    for (int i = tid; i < 500; i += 256) {
        l0 += partials[i];
        l1 += partials[500 + i];
    }
#pragma unroll
    for (int s = 32; s >= 1; s >>= 1) {
        l0 += __shfl_xor(l0, s, 64);
        l1 += __shfl_xor(l1, s, 64);
    }
    if ((tid & 63) == 0) {
        red[(tid >> 6) * 2]     = l0;
        red[(tid >> 6) * 2 + 1] = l1;
    }
    for (int i = tid; i < 500; i += 256) {
        sFic[i] = F_ic[ch * NPTS + i];
        sPc[i]  = P_c[ch * NPTS + i];
    }
    __syncthreads();
    const float inv0 = 1.f / (red[0] + red[2] + red[4] + red[6]);
    const float inv1 = 1.f / (red[1] + red[3] + red[5] + red[7]);

    float* cd_row  = dcat + (size_t)ch * 500;            // rows   0..127
    float* sid_row = dcat + (size_t)(128 + ch) * 500;    // rows 128..255
    float* id_row  = dcat + (size_t)(256 + ch) * 500;    // rows 256..383
    float* spd_row = dcat + (size_t)(384 + ch) * 500;    // rows 384..511

    // pass 1: full-row diff into LDS; global write only for this half
    for (int n = tid; n < 500; n += 256) {
        float maxI = -FLT_MAX, maxP = -FLT_MAX;
#pragma unroll
        for (int j = 0; j < NP12; ++j) {
            int idx  = inds[n * NP12 + j];
            float wv = w_ct[n * NP12 + j] * inv0;
            maxI = fmaxf(maxI, sFic[idx] * wv);
            maxP = fmaxf(maxP, sPc[idx] * wv);
        }
        float idv = F_it[ch * NPTS + n] - maxI;
        float cdv = P_ct[ch * NPTS + n] - maxP;
        sID[n] = idv;
        sCD[n] = cdv;
        if (n >= n0 && n < n0 + 250) {
            id_row[n] = idv;
            cd_row[n] = cdv;
        }
    }
    __syncthreads();
    // pass 2: sdiff gather for this half only
    for (int n = n0 + tid; n < n0 + 250; n += 256) {
        float maxP = -FLT_MAX, maxI = -FLT_MAX;
#pragma unroll
        for (int j = 0; j < NP12; ++j) {
            int idx  = inds_self2[n * NP12 + j];
            float wv = w_cc[n * NP12 + j] * inv1;
            maxP = fmaxf(maxP, sCD[idx] * wv);
            maxI = fmaxf(maxI, sID[idx] * wv);
        }
        spd_row[n] = maxP;
        sid_row[n] = maxI;
    }
}

// ---------------------------------------------------------------------------
// GEMM core (verified r4/r8): Y[r,n] = bias + sum_k W[r*ldW+kOffW+k]*X[k,n].
// Optional Xb/Xc/Xd: stages X+Xb+Xc+Xd elementwise (sums split-K partials
// for free). wave -> 2 rows x 64 cols; K chunked by 32 in LDS; register
// double-buffer. No lambdas (clang crash, r3). Over-reads <=12 floats past
// last row end: ws guard gaps cover it.
// ---------------------------------------------------------------------------
__device__ __forceinline__ void gemm_dev(
        const float* __restrict__ W, int ldW, int kOffW,
        const float* __restrict__ Bv,
        const float* __restrict__ X, const float* __restrict__ Xb,
        const float* __restrict__ Xc, const float* __restrict__ Xd, int K,
        float* __restrict__ Y, int r0, int col0,
        int mode, const float* __restrict__ aux, float* Xs) {
    const int tid  = threadIdx.x;
    const int lane = tid & 63;
    const int n    = col0 + lane;
    const int srow = tid >> 3;
    const int scol = (tid & 7) * 8;
    const int coloff = col0 + scol;

    float acc0 = Bv ? Bv[r0]     : 0.f;
    float acc1 = Bv ? Bv[r0 + 1] : 0.f;

    const int nchunks = K >> 5;

    size_t row0 = (size_t)srow * NPTS + coloff;
    float4 ra = *(const float4*)(X + row0);
    float4 rb = *(const float4*)(X + row0 + 4);
    if (Xb) {
        float4 ba = *(const float4*)(Xb + row0);
        float4 bb = *(const float4*)(Xb + row0 + 4);
        ra.x += ba.x; ra.y += ba.y; ra.z += ba.z; ra.w += ba.w;
        rb.x += bb.x; rb.y += bb.y; rb.z += bb.z; rb.w += bb.w;
        if (Xc) {
            float4 ca = *(const float4*)(Xc + row0);
            float4 cb = *(const float4*)(Xc + row0 + 4);
            float4 da = *(const float4*)(Xd + row0);
            float4 db = *(const float4*)(Xd + row0 + 4);
            ra.x += ca.x + da.x; ra.y += ca.y + da.y;
            ra.z += ca.z + da.z; ra.w += ca.w + da.w;
            rb.x += cb.x + db.x; rb.y += cb.y + db.y;
            rb.z += cb.z + db.z; rb.w += cb.w + db.w;
        }
    }

    for (int c = 0; c < nchunks; ++c) {
        __syncthreads();
        float* dsh = &Xs[srow * 64 + scol];
        *(float4*)dsh       = ra;
        *(float4*)(dsh + 4) = rb;
        if (c + 1 < nchunks) {
            size_t row = (size_t)((c + 1) * 32 + srow) * NPTS + coloff;
            ra = *(const float4*)(X + row);
            rb = *(const float4*)(X + row + 4);
            if (Xb) {
                float4 ba = *(const float4*)(Xb + row);
                float4 bb = *(const float4*)(Xb + row + 4);
                ra.x += ba.x; ra.y += ba.y; ra.z += ba.z; ra.w += ba.w;
                rb.x += bb.x; rb.y += bb.y; rb.z += bb.z; rb.w += bb.w;
                if (Xc) {
                    float4 ca = *(const float4*)(Xc + row);
                    float4 cb = *(const float4*)(Xc + row + 4);
                    float4 da = *(const float4*)(Xd + row);
                    float4 db = *(const float4*)(Xd + row + 4);
                    ra.x += ca.x + da.x; ra.y += ca.y + da.y;
                    ra.z += ca.z + da.z; ra.w += ca.w + da.w;
                    rb.x += cb.x + db.x; rb.y += cb.y + db.y;
                    rb.z += cb.z + db.z; rb.w += cb.w + db.w;
                }
            }
        }
        __syncthreads();
        const float* w0 = &W[(size_t)r0 * ldW + kOffW + c * 32];
        const float* w1 = w0 + ldW;
#pragma unroll
        for (int k = 0; k < 32; ++k) {
            float xv = Xs[k * 64 + lane];
            acc0 = fmaf(w0[k], xv, acc0);
            acc1 = fmaf(w1[k], xv, acc1);
        }
    }

    if (n < NPTS) {
        float v0 = acc0, v1 = acc1;
        if (mode == 1) { v0 = lrelu(v0); v1 = lrelu(v1); }
        else if (mode == 2) {
            v0 *= aux[r0 * NPTS + n];
            v1 *= aux[(r0 + 1) * NPTS + n];
        }
        Y[r0 * NPTS + n]       = v0;
        Y[(r0 + 1) * NPTS + n] = v1;
    }
}

// generic single GEMM (sums up to 4 partial-X inputs). grid=(8, Cout/8).
__global__ __launch_bounds__(256) void gemm_single_kernel(
        const float* __restrict__ W, const float* __restrict__ Bv,
        const float* __restrict__ X, const float* __restrict__ Xb,
        const float* __restrict__ Xc, const float* __restrict__ Xd, int K,
        float* __restrict__ Y, int mode, const float* __restrict__ aux) {
    __shared__ __align__(16) float Xs[32 * 64];
    const int wave = __builtin_amdgcn_readfirstlane(threadIdx.x >> 6);
    gemm_dev(W, K, 0, Bv, X, Xb, Xc, Xd, K, Y,
             blockIdx.y * 8 + wave * 2, blockIdx.x * 64, mode, aux, Xs);
}

// gemmA split-K x4: grid=(8,20,4); part p covers dcat rows [p*128,(p+1)*128).
// Bias carried by part 0 only; gemmB sums the 4 parts while staging.
__global__ __launch_bounds__(256) void gemmA_splitk_kernel(
        const float* __restrict__ Wcomb1, const float* __restrict__ bcomb1,
        const float* __restrict__ dcat,
        float* __restrict__ part0, float* __restrict__ part1,
        float* __restrict__ part2, float* __restrict__ part3) {
    __shared__ __align__(16) float Xs[32 * 64];
    const int wave = __builtin_amdgcn_readfirstlane(threadIdx.x >> 6);
    const int p = blockIdx.z;
    float* dst = p == 0 ? part0 : p == 1 ? part1 : p == 2 ? part2 : part3;
    gemm_dev(Wcomb1, 512, p * 128, p == 0 ? bcomb1 : (const float*)nullptr,
             dcat + (size_t)p * 128 * NPTS, nullptr, nullptr, nullptr, 128,
             dst, blockIdx.y * 8 + wave * 2, blockIdx.x * 64, 0, nullptr, Xs);
}

// pn3 split-K x8: grid=(8,20,8); part p handles k in [p*128,(p+1)*128).
// Parts contiguous at stride 80000 (written exact, read exact by final).
__global__ __launch_bounds__(256) void gemm_splitk_kernel(
        const float* __restrict__ W, const float* __restrict__ X,
        float* __restrict__ part) {
    __shared__ __align__(16) float Xs[32 * 64];
    const int wave = __builtin_amdgcn_readfirstlane(threadIdx.x >> 6);
    const int p = blockIdx.z;
    gemm_dev(W, 1024, p * 128, nullptr,
             X + (size_t)p * 128 * NPTS, nullptr, nullptr, nullptr, 128,
             part + (size_t)p * 80000,
             blockIdx.y * 8 + wave * 2, blockIdx.x * 64, 0, nullptr, Xs);
}

// ---------------------------------------------------------------------------
// final: out = current_feat + mean_4( target_feat * (sum_8 part + b_pn3) )
// ---------------------------------------------------------------------------
__global__ __launch_bounds__(256) void final_kernel(
        const float* __restrict__ current_feat, const float* __restrict__ target_feat,
        const float* __restrict__ part, const float* __restrict__ b_pn3,
        const int* __restrict__ inds_pp, float* __restrict__ out) {
    int gid = blockIdx.x * 256 + threadIdx.x;
    if (gid >= 160 * NPTS) return;
    int ch = gid / NPTS;
    int n  = gid % NPTS;
    float bias = b_pn3[ch];
    int idxv[NPP];
#pragma unroll
    for (int j = 0; j < NPP; ++j) idxv[j] = inds_pp[n * NPP + j];
    float s = 0.f;
#pragma unroll
    for (int j = 0; j < NPP; ++j) {
        int m = ch * NPTS + idxv[j];
        float v = bias;
#pragma unroll
        for (int q = 0; q < 8; ++q) v += part[q * 80000 + m];
        s += target_feat[m] * v;
    }
    out[gid] = current_feat[gid] + 0.25f * s;
}

// ---------------------------------------------------------------------------
extern "C" void kernel_launch(void* const* d_in, const int* in_sizes, int n_in,
                              void* d_out, int out_size, void* d_ws, size_t ws_size,
                              hipStream_t stream) {
    const float* img          = (const float*)d_in[0];
    const float* cloud        = (const float*)d_in[1];
    const float* img_tar      = (const float*)d_in[2];
    const float* cloud_tar    = (const float*)d_in[3];
    const float* current_feat = (const float*)d_in[4];
    const float* target_feat  = (const float*)d_in[5];
    const float* W_conv1  = (const float*)d_in[6];
    const float* b_conv1  = (const float*)d_in[7];
    const float* W_conv2  = (const float*)d_in[8];
    const float* b_conv2  = (const float*)d_in[9];
    const float* W_pconv1 = (const float*)d_in[10];
    const float* b_pconv1 = (const float*)d_in[11];
    const float* W_pconv2 = (const float*)d_in[12];
    const float* b_pconv2 = (const float*)d_in[13];
    const float* W_fc1    = (const float*)d_in[14];
    const float* b_fc1    = (const float*)d_in[15];
    const float* W_fc2    = (const float*)d_in[16];
    const float* b_fc2    = (const float*)d_in[17];
    const float* W_fuse2  = (const float*)d_in[18];
    const float* b_fuse2  = (const float*)d_in[19];
    const float* W_pn1    = (const float*)d_in[20];
    const float* b_pn1    = (const float*)d_in[21];
    const float* W_pn2    = (const float*)d_in[22];
    const float* b_pn2    = (const float*)d_in[23];
    const float* W_pn3    = (const float*)d_in[24];
    const float* b_pn3    = (const float*)d_in[25];

    // ws arena (floats); 64-float guard gaps cover GEMM staging over-reads.
    float* ws = (float*)d_ws;
    size_t off = 0;
    auto alloc = [&](size_t nfl) { float* q = ws + off; off += ((nfl + 63) & ~size_t(63)) + 64; return q; };
    int*   inds       = (int*)alloc(6000);
    int*   inds_self2 = (int*)alloc(6000);
    int*   inds_pp    = (int*)alloc(2000);
    float* w_ct       = alloc(6000);
    float* w_cc       = alloc(6000);
    float* partials   = alloc(1000);
    float* P_ct       = alloc(64000);
    float* P_c        = alloc(64000);
    float* F_it       = alloc(64000);
    float* F_ic       = alloc(64000);
    float* dcat       = alloc(256000);   // [cd;sid;id;spd] 512x500
    float* fpart0     = alloc(80000);    // gemmA split-K partials
    float* fpart1     = alloc(80000);
    float* fpart2     = alloc(80000);
    float* fpart3     = alloc(80000);
    float* x2         = alloc(512000);
    float* pn3part    = alloc(640000);   // 8 x 80000, stride 80000
    float* Wcomb1     = alloc(81920);    // 160x512
    float* bcomb1     = alloc(160);
    float* Wcomb2     = alloc(163840);   // 1024x160
    float* bcomb2     = alloc(1024);
    float* out        = (float*)d_out;

    // K1: knn + featchain(both layers) + compose, 1468 blocks
    prep_kernel<<<1468, 256, 0, stream>>>(
        cloud, cloud_tar, img, img_tar,
        W_pconv1, b_pconv1, W_pconv2, b_pconv2,
        W_conv1, b_conv1, W_conv2, b_conv2,
        W_pn1, b_pn1, W_pn2, b_pn2,
        W_fc1, b_fc1, W_fc2, b_fc2, W_fuse2, b_fuse2,
        inds, inds_self2, inds_pp, w_ct, w_cc, partials,
        P_ct, P_c, F_it, F_ic,
        Wcomb2, bcomb2, Wcomb1, bcomb1);

    // K2: diff + sdiff -> dcat (256 blocks: channel x column-half)
    diffsdiff_kernel<<<256, 256, 0, stream>>>(
        F_it, F_ic, P_ct, P_c, inds, inds_self2, w_ct, w_cc, partials, dcat);

    // K3: fuse_t_c partials = Wcomb1 @ dcat + bcomb1 (split-K x4)
    gemmA_splitk_kernel<<<dim3(8, 20, 4), 256, 0, stream>>>(
        Wcomb1, bcomb1, dcat, fpart0, fpart1, fpart2, fpart3);

    // K4: x2 = lrelu(Wcomb2 @ (sum fparts) + bcomb2)  (1024,500), K=160
    gemm_single_kernel<<<dim3(8, 128), 256, 0, stream>>>(
        Wcomb2, bcomb2, fpart0, fpart1, fpart2, fpart3, 160, x2, 1, nullptr);

    // K5: pn3 partials (split-K x8)
    gemm_splitk_kernel<<<dim3(8, 20, 8), 256, 0, stream>>>(W_pn3, x2, pn3part);

    // K6: final combine + 4-NN mean
    final_kernel<<<313, 256, 0, stream>>>(current_feat, target_feat, pn3part, b_pn3,
                                          inds_pp, out);
}